// Round 10
// baseline (159.656 us; speedup 1.0000x reference)
//
#include <hip/hip_runtime.h>
#include <stdint.h>
#include <math.h>

#define N 8192
#define CAP 8
#define OVF_MAX 4096

// async global->LDS DMA, 16 B per lane (lane-contiguous source, uniform dest)
__device__ __forceinline__ void gl_lds16(const void* g, void* l) {
    __builtin_amdgcn_global_load_lds(
        (const __attribute__((address_space(1))) void*)g,
        (__attribute__((address_space(3))) void*)l, 16, 0, 0);
}

// ================= Sort stage (bitonic, exact argsort) =================
// key = (~monotone(score) << 32) | index; ascending sort == stable argsort
// of -scores. Network split: local k<=2048 (s1), k=4096 (s2), k=8192 (s3).

__global__ __launch_bounds__(1024) void k_sort1(const float* __restrict__ scores,
                                                uint64_t* __restrict__ keys,
                                                uint32_t* __restrict__ cnt,
                                                uint32_t* __restrict__ ovfc) {
    __shared__ uint64_t sk[2048];
    int b = blockIdx.x, t = threadIdx.x;
    int base = b * 2048;
    // zero the per-row packed-entry counters (must happen before k_mask).
    cnt[base + t] = 0;
    cnt[base + t + 1024] = 0;
    if (b == 0 && t == 0) *ovfc = 0;
    for (int e = 0; e < 2; ++e) {
        int li = t + e * 1024;
        int i = base + li;
        uint32_t sb = __float_as_uint(scores[i]);
        sb = (sb & 0x80000000u) ? ~sb : (sb | 0x80000000u);
        sk[li] = ((uint64_t)(~sb) << 32) | (uint32_t)i;
    }
    __syncthreads();
    for (int k = 2; k <= 2048; k <<= 1) {
        for (int j = k >> 1; j > 0; j >>= 1) {
            for (int e = 0; e < 2; ++e) {
                int li = t + e * 1024;
                int lixj = li ^ j;
                if (lixj > li) {
                    int gi = base + li;
                    bool up = ((gi & k) == 0);
                    uint64_t a = sk[li], c = sk[lixj];
                    if ((a > c) == up) { sk[li] = c; sk[lixj] = a; }
                }
            }
            __syncthreads();
        }
    }
    for (int e = 0; e < 2; ++e) { int li = t + e * 1024; keys[base + li] = sk[li]; }
}

// k=4096: cross pass j=2048 read from global (element-wise), then local j<=1024.
__global__ __launch_bounds__(1024) void k_sort2(const uint64_t* __restrict__ keys,
                                                uint64_t* __restrict__ keys2) {
    __shared__ uint64_t sk[2048];
    int b = blockIdx.x, t = threadIdx.x;
    int base = b * 2048;
    for (int e = 0; e < 2; ++e) {
        int li = t + e * 1024;
        int i = base + li;
        uint64_t a = keys[i], c = keys[i ^ 2048];
        bool up = ((i & 4096) == 0);
        bool lowpos = ((i & 2048) == 0);
        uint64_t mn = a < c ? a : c, mx = a < c ? c : a;
        sk[li] = (up == lowpos) ? mn : mx;
    }
    __syncthreads();
    for (int j = 1024; j > 0; j >>= 1) {
        for (int e = 0; e < 2; ++e) {
            int li = t + e * 1024;
            int lixj = li ^ j;
            if (lixj > li) {
                int gi = base + li;
                bool up = ((gi & 4096) == 0);
                uint64_t a = sk[li], c = sk[lixj];
                if ((a > c) == up) { sk[li] = c; sk[lixj] = a; }
            }
        }
        __syncthreads();
    }
    for (int e = 0; e < 2; ++e) { int li = t + e * 1024; keys2[base + li] = sk[li]; }
}

// k=8192 (up=true everywhere): cross passes j=4096,2048 from global, local
// j<=1024, then fused gather of boxes/scores into sorted order.
__global__ __launch_bounds__(1024) void k_sort3(const uint64_t* __restrict__ keys2,
                                                const float4* __restrict__ boxes,
                                                const float* __restrict__ scores,
                                                float4* __restrict__ bs,
                                                float* __restrict__ ss) {
    __shared__ uint64_t sk[2048];
    int b = blockIdx.x, t = threadIdx.x;
    int base = b * 2048;
    for (int e = 0; e < 2; ++e) {
        int li = t + e * 1024;
        int i = base + li;
        uint64_t a0 = keys2[i], a1 = keys2[i ^ 4096];
        bool low0 = ((i & 4096) == 0);
        uint64_t v = low0 ? (a0 < a1 ? a0 : a1) : (a0 < a1 ? a1 : a0);
        int q = i ^ 2048;
        uint64_t b0 = keys2[q], b1 = keys2[q ^ 4096];
        bool lowq = ((q & 4096) == 0);
        uint64_t vq = lowq ? (b0 < b1 ? b0 : b1) : (b0 < b1 ? b1 : b0);
        bool low2 = ((i & 2048) == 0);
        sk[li] = low2 ? (v < vq ? v : vq) : (v < vq ? vq : v);
    }
    __syncthreads();
    for (int j = 1024; j > 0; j >>= 1) {
        for (int e = 0; e < 2; ++e) {
            int li = t + e * 1024;
            int lixj = li ^ j;
            if (lixj > li) {
                uint64_t a = sk[li], c = sk[lixj];
                if (a > c) { sk[li] = c; sk[lixj] = a; }   // up = true
            }
        }
        __syncthreads();
    }
    for (int e = 0; e < 2; ++e) {
        int li = t + e * 1024;
        int gi = base + li;
        uint32_t idx = (uint32_t)sk[li];
        bs[gi] = boxes[idx];
        ss[gi] = scores[idx];
    }
}

// ---------------- Suppression bitmask -> sparse packed ----------------
// One wave per upper-triangle (R, word) tile; 8256 tiles = 2064 blocks x 4
// waves, perfectly balanced, zero barriers. Per row: diag word to diag[],
// nonzero off-diagonal words appended (atomicAdd cnt) to transposed
// pkT[e*N+row]; entries beyond CAP go to a tiny global overflow list.
__global__ __launch_bounds__(256) void k_mask(const float4* __restrict__ bs,
                                              ulonglong2* __restrict__ pkT,
                                              uint32_t* __restrict__ cnt,
                                              uint64_t* __restrict__ diag,
                                              ulonglong2* __restrict__ ovf,
                                              uint32_t* __restrict__ ovfc) {
    __shared__ float4 rb[4][64];
    __shared__ float  ra[4][64];
    int t = threadIdx.x;
    int lane = t & 63;
    int wv = t >> 6;
    int tile = blockIdx.x * 4 + wv;          // 0..8255

    // decode tile -> (R, word): off(R) = 128R - R(R-1)/2, word >= R
    int R = (int)((257.0 - sqrt(66049.0 - 8.0 * (double)tile)) * 0.5);
    while (128 * (R + 1) - ((R + 1) * R) / 2 <= tile) ++R;   // safety correction
    while (128 * R - (R * (R - 1)) / 2 > tile) --R;
    int word = R + tile - (128 * R - (R * (R - 1)) / 2);

    {   // stage this wave's 64 row boxes (wave-private LDS, no barrier needed)
        float4 b = bs[R * 64 + lane];
        rb[wv][lane] = b;
        ra[wv][lane] = ((b.z - b.x) + 1.0f) * ((b.w - b.y) + 1.0f);
    }
    int col = word * 64 + lane;
    float4 cb = bs[col];
    float ca = ((cb.z - cb.x) + 1.0f) * ((cb.w - cb.y) + 1.0f);

    for (int r = 0; r < 64; ++r) {
        int row = R * 64 + r;
        float4 rbv = rb[wv][r];
        float ix1 = fmaxf(rbv.x, cb.x);
        float iy1 = fmaxf(rbv.y, cb.y);
        float ix2 = fminf(rbv.z, cb.z);
        float iy2 = fminf(rbv.w, cb.w);
        float iw = fmaxf((ix2 - ix1) + 1.0f, 0.0f);
        float ih = fmaxf((iy2 - iy1) + 1.0f, 0.0f);
        float inter = iw * ih;
        float uni = (ra[wv][r] + ca) - inter;   // matches ref order
        float iou = inter / uni;                // IEEE div, matches numpy ref
        bool pred = (iou > 0.5f) && (col > row);
        uint64_t bal = __ballot(pred);
        if (lane == 0) {
            if (word == R) {
                diag[row] = bal;                 // intra-chunk word
            } else if (bal) {
                uint32_t pos = atomicAdd(&cnt[row], 1u);
                if (pos < CAP) {
                    ulonglong2 v;
                    v.x = bal; v.y = (unsigned long long)word;
                    pkT[(size_t)pos * N + row] = v;
                } else {
                    uint32_t op = atomicAdd(ovfc, 1u);
                    if (op < OVF_MAX) {
                        ulonglong2 v;
                        v.x = bal;
                        v.y = (unsigned long long)word |
                              ((unsigned long long)row << 32);
                        ovf[op] = v;
                    }
                }
            }
        }
    }
}

// ---------------- Sparse single-wave greedy scan (LDS-staged) ----------------
// 64 threads, zero barriers. Entries DMA'd into double-buffered LDS via
// global_load_lds (no VGPR prefetch arrays -- regalloc refused them twice:
// VGPR_Count 80/48 < needed). Per chunk: vmcnt(0) drains last chunk's DMA
// (issued a full chunk ago -> ~free), issue next chunk's DMA, read entries
// into named locals, sparse scalar recurrence, LDS atomicOr scatter.
__global__ __launch_bounds__(64, 1) void k_scan(const ulonglong2* __restrict__ pkT,
                                                const uint32_t* __restrict__ cnt,
                                                const uint64_t* __restrict__ diag,
                                                const ulonglong2* __restrict__ ovf,
                                                const uint32_t* __restrict__ ovfc,
                                                uint64_t* __restrict__ keepw) {
    __shared__ uint64_t sh_remv[128];
    __shared__ ulonglong2 pk_lds[2][CAP][64];
    const int lane = threadIdx.x;
    sh_remv[lane] = 0;
    sh_remv[64 + lane] = 0;
    const int novf = min((int)*ovfc, OVF_MAX);

    uint64_t dA = diag[lane];        uint32_t cA = cnt[lane];
    uint64_t dB = diag[64 + lane];   uint32_t cB = cnt[64 + lane];
    // prologue: DMA chunk 0's entries into buffer 0
#pragma unroll
    for (int e = 0; e < CAP; ++e)
        gl_lds16(pkT + (size_t)e * N + lane, (void*)&pk_lds[0][e][0]);

#define PROCESS(C_, PAR, CD, CC)                                               \
    {                                                                          \
        const int c_ = (C_);                                                   \
        uint64_t d_cur = CD;                                                   \
        uint32_t c_cur = CC;                                                   \
        /* drain this chunk's DMA (issued one full chunk ago) */               \
        asm volatile("s_waitcnt vmcnt(0)" ::: "memory");                       \
        /* issue next chunk's DMA + depth-2 diag/cnt register refill */        \
        if (c_ + 1 < 128) {                                                    \
            _Pragma("unroll")                                                  \
            for (int e = 0; e < CAP; ++e)                                      \
                gl_lds16(pkT + (size_t)e * N + (c_ + 1) * 64 + lane,           \
                         (void*)&pk_lds[1 - (PAR)][e][0]);                     \
        }                                                                      \
        if (c_ + 2 < 128) {                                                    \
            int nb2 = (c_ + 2) * 64 + lane;                                    \
            CD = diag[nb2];                                                    \
            CC = cnt[nb2];                                                     \
        }                                                                      \
        /* read this chunk's entries into named (SROA-proof) locals */         \
        ulonglong2 n0 = pk_lds[(PAR)][0][lane], n1 = pk_lds[(PAR)][1][lane];   \
        ulonglong2 n2 = pk_lds[(PAR)][2][lane], n3 = pk_lds[(PAR)][3][lane];   \
        ulonglong2 n4 = pk_lds[(PAR)][4][lane], n5 = pk_lds[(PAR)][5][lane];   \
        ulonglong2 n6 = pk_lds[(PAR)][6][lane], n7 = pk_lds[(PAR)][7][lane];   \
        /* sparse scalar serial recurrence */                                  \
        uint64_t nzv = __ballot(d_cur != 0);                                   \
        uint32_t nlo = __builtin_amdgcn_readfirstlane((uint32_t)nzv);          \
        uint32_t nhi = __builtin_amdgcn_readfirstlane((uint32_t)(nzv >> 32));  \
        uint64_t nz = ((uint64_t)nhi << 32) | nlo;                             \
        uint32_t mlo = (uint32_t)d_cur, mhi = (uint32_t)(d_cur >> 32);         \
        asm volatile("s_waitcnt lgkmcnt(0)" ::: "memory");                     \
        uint64_t wvv = sh_remv[c_];                                            \
        uint32_t wlo = __builtin_amdgcn_readfirstlane((uint32_t)wvv);          \
        uint32_t whi = __builtin_amdgcn_readfirstlane((uint32_t)(wvv >> 32));  \
        uint64_t w_ = ((uint64_t)whi << 32) | wlo;                             \
        while (nz) {                                                           \
            int i = (int)__builtin_ctzll(nz);                                  \
            nz &= nz - 1;                                                      \
            if (!((w_ >> i) & 1ull)) {                                         \
                uint32_t lo = __builtin_amdgcn_readlane(mlo, i);               \
                uint32_t hi = __builtin_amdgcn_readlane(mhi, i);               \
                w_ |= ((uint64_t)hi << 32) | lo;                               \
            }                                                                  \
        }                                                                      \
        if (lane == 0) sh_remv[c_] = w_;  /* final word; keepw written later */\
        if (!((w_ >> lane) & 1ull)) {  /* kept: scatter future words */        \
            if (0 < (int)c_cur) atomicOr((unsigned long long*)&sh_remv[(int)n0.y], (unsigned long long)n0.x); \
            if (1 < (int)c_cur) atomicOr((unsigned long long*)&sh_remv[(int)n1.y], (unsigned long long)n1.x); \
            if (2 < (int)c_cur) atomicOr((unsigned long long*)&sh_remv[(int)n2.y], (unsigned long long)n2.x); \
            if (3 < (int)c_cur) atomicOr((unsigned long long*)&sh_remv[(int)n3.y], (unsigned long long)n3.x); \
            if (4 < (int)c_cur) atomicOr((unsigned long long*)&sh_remv[(int)n4.y], (unsigned long long)n4.x); \
            if (5 < (int)c_cur) atomicOr((unsigned long long*)&sh_remv[(int)n5.y], (unsigned long long)n5.x); \
            if (6 < (int)c_cur) atomicOr((unsigned long long*)&sh_remv[(int)n6.y], (unsigned long long)n6.x); \
            if (7 < (int)c_cur) atomicOr((unsigned long long*)&sh_remv[(int)n7.y], (unsigned long long)n7.x); \
        }                                                                      \
        uint64_t ovb = __ballot(c_cur > CAP);  /* exact overflow completion */ \
        if (ovb) {                                                             \
            for (int e = lane; e < novf; e += 64) {                            \
                ulonglong2 en = ovf[e];                                        \
                int erow = (int)(en.y >> 32);                                  \
                if ((erow >> 6) == c_ && !((w_ >> (erow & 63)) & 1ull))        \
                    atomicOr((unsigned long long*)&sh_remv[(int)(uint32_t)en.y],\
                             (unsigned long long)en.x);                        \
            }                                                                  \
        }                                                                      \
    }

    for (int cc = 0; cc < 128; cc += 2) {
        PROCESS(cc,     0, dA, cA)
        PROCESS(cc + 1, 1, dB, cB)
    }
#undef PROCESS

    // single coalesced keep write-out
    asm volatile("s_waitcnt lgkmcnt(0)" ::: "memory");
    keepw[lane] = ~sh_remv[lane];
    keepw[64 + lane] = ~sh_remv[64 + lane];
}

// ---------------- Masked outputs ----------------
__global__ void k_out(const float4* __restrict__ bs, const float* __restrict__ ss,
                      const uint64_t* __restrict__ keepw, float* __restrict__ out) {
    int i = blockIdx.x * blockDim.x + threadIdx.x;
    uint64_t wv = keepw[i >> 6];
    float m = ((wv >> (i & 63)) & 1ull) ? 1.0f : 0.0f;
    float4 b = bs[i];
    float4 ob;
    ob.x = b.x * m; ob.y = b.y * m; ob.z = b.z * m; ob.w = b.w * m;
    ((float4*)out)[i] = ob;
    out[4 * N + i] = ss[i] * m;
    out[5 * N + i] = m;
}

extern "C" void kernel_launch(void* const* d_in, const int* in_sizes, int n_in,
                              void* d_out, int out_size, void* d_ws, size_t ws_size,
                              hipStream_t stream) {
    const float* boxes  = (const float*)d_in[0];   // 8192 x 4 f32
    const float* scores = (const float*)d_in[1];   // 8192 f32

    char* ws = (char*)d_ws;
    float4*     bs    = (float4*)(ws + 0);          // 131072 B
    float*      ss    = (float*)(ws + 131072);      //  32768 B
    uint64_t*   keepw = (uint64_t*)(ws + 163840);   //   1024 B
    uint32_t*   cnt   = (uint32_t*)(ws + 164864);   //  32768 B
    uint64_t*   diag  = (uint64_t*)(ws + 197632);   //  65536 B
    uint32_t*   ovfc  = (uint32_t*)(ws + 263168);   //      4 B (padded)
    ulonglong2* ovf   = (ulonglong2*)(ws + 263680); //  65536 B (4096 x 16)
    uint64_t*   keys  = (uint64_t*)(ws + 329216);   //  65536 B
    uint64_t*   keys2 = (uint64_t*)(ws + 394752);   //  65536 B
    ulonglong2* pkT   = (ulonglong2*)(ws + 524288); // 1048576 B (CAP x N x 16)

    k_sort1<<<4, 1024, 0, stream>>>(scores, keys, cnt, ovfc);
    k_sort2<<<4, 1024, 0, stream>>>(keys, keys2);
    k_sort3<<<4, 1024, 0, stream>>>(keys2, (const float4*)boxes, scores, bs, ss);
    k_mask <<<2064, 256, 0, stream>>>(bs, pkT, cnt, diag, ovf, ovfc);
    k_scan <<<1, 64, 0, stream>>>(pkT, cnt, diag, ovf, ovfc, keepw);
    k_out  <<<N / 256, 256, 0, stream>>>(bs, ss, keepw, (float*)d_out);
}